// Round 3
// baseline (139.483 us; speedup 1.0000x reference)
//
#include <hip/hip_runtime.h>

#define FIN  64
#define FOUT 64
#define HI   128
#define WI   128
#define HO   126
#define WO   126
#define TH   16      // output tile rows per block
#define TW   32      // output tile cols per block
#define PX   2       // pixels per thread (1x2 strip)
#define OCH  8       // output channels per block
#define HR   18      // TH + 2
#define HC   34      // TW + 2
#define LSTR 36      // padded LDS row stride (16B-aligned rows)
#define NSTAGE 3     // ceil(HR*HC / 256) = ceil(612/256)

__global__ __launch_bounds__(256, 4) void fused_dwconv_combine(
    const float* __restrict__ x,  const float* __restrict__ Wf,
    const float* __restrict__ bf, const float* __restrict__ Wc,
    const float* __restrict__ bc, float* __restrict__ out)
{
    __shared__ float xs[2][HR * LSTR];

    const int tid = threadIdx.x;
    const int tx  = tid & 15;       // 0..15 -> output cols 2tx, 2tx+1
    const int ty  = tid >> 4;       // 0..15 -> output row
    const int tY  = blockIdx.x >> 2;    // 0..7 row tile
    const int tX  = blockIdx.x & 3;     // 0..3 col tile
    const int o0  = blockIdx.y * OCH;
    const int b   = blockIdx.z;

    const int row0 = tY * TH;
    const int col0 = tX * TW;

    // staging map: computed once, only the channel base advances
    int goff[NSTAGE], loff[NSTAGE];
#pragma unroll
    for (int k = 0; k < NSTAGE; ++k) {
        int e = tid + k * 256;
        if (e < HR * HC) {
            int r = e / HC, c = e - r * HC;
            int gy = min(row0 + r, HI - 1);
            int gx = min(col0 + c, WI - 1);
            goff[k] = gy * WI + gx;
            loff[k] = r * LSTR + c;
        } else { goff[k] = 0; loff[k] = -1; }
    }

    const float* xb = x + (size_t)b * FIN * HI * WI;

    float acc[OCH][PX];
#pragma unroll
    for (int oo = 0; oo < OCH; ++oo) {
        float bcv = bc[o0 + oo];
#pragma unroll
        for (int p = 0; p < PX; ++p) acc[oo][p] = bcv;
    }

    // stage channel 0 into buffer 0
#pragma unroll
    for (int k = 0; k < NSTAGE; ++k)
        if (loff[k] >= 0) xs[0][loff[k]] = xb[goff[k]];

    auto body = [&](int i, int cur) {
        // prefetch next channel into regs (hides HBM/L2 latency under compute)
        float st[NSTAGE];
        if (i + 1 < FIN) {
            const float* xp = xb + (size_t)(i + 1) * (HI * WI);
#pragma unroll
            for (int k = 0; k < NSTAGE; ++k)
                if (loff[k] >= 0) st[k] = xp[goff[k]];
        }

        __syncthreads();   // prev writes to xs[cur] visible; prev reads done

        // 3x4 window, fully register-resident (12 floats, static indices)
        float w00, w01, w02, w03, w10, w11, w12, w13, w20, w21, w22, w23;
        {
            const float* r0 = &xs[cur][(ty + 0) * LSTR + 2 * tx];
            const float* r1 = &xs[cur][(ty + 1) * LSTR + 2 * tx];
            const float* r2 = &xs[cur][(ty + 2) * LSTR + 2 * tx];
            w00 = r0[0]; w01 = r0[1]; w02 = r0[2]; w03 = r0[3];
            w10 = r1[0]; w11 = r1[1]; w12 = r1[2]; w13 = r1[3];
            w20 = r2[0]; w21 = r2[1]; w22 = r2[2]; w23 = r2[3];
        }

#pragma unroll
        for (int oo = 0; oo < OCH; ++oo) {
            const int o = o0 + oo;
            const float* wp = Wf + ((size_t)o * FIN + i) * 9;  // uniform -> s_load
            const float bfv = bf[o * FIN + i];
            const float wcv = Wc[o * FIN + i];
            float s0 = bfv, s1 = bfv;
            s0 = fmaf(wp[0], w00, s0);  s1 = fmaf(wp[0], w01, s1);
            s0 = fmaf(wp[1], w01, s0);  s1 = fmaf(wp[1], w02, s1);
            s0 = fmaf(wp[2], w02, s0);  s1 = fmaf(wp[2], w03, s1);
            s0 = fmaf(wp[3], w10, s0);  s1 = fmaf(wp[3], w11, s1);
            s0 = fmaf(wp[4], w11, s0);  s1 = fmaf(wp[4], w12, s1);
            s0 = fmaf(wp[5], w12, s0);  s1 = fmaf(wp[5], w13, s1);
            s0 = fmaf(wp[6], w20, s0);  s1 = fmaf(wp[6], w21, s1);
            s0 = fmaf(wp[7], w21, s0);  s1 = fmaf(wp[7], w22, s1);
            s0 = fmaf(wp[8], w22, s0);  s1 = fmaf(wp[8], w23, s1);
            acc[oo][0] = fmaf(wcv, fmaxf(s0, 0.f), acc[oo][0]);
            acc[oo][1] = fmaf(wcv, fmaxf(s1, 0.f), acc[oo][1]);
        }

        // commit prefetched channel into the other buffer
        if (i + 1 < FIN) {
#pragma unroll
            for (int k = 0; k < NSTAGE; ++k)
                if (loff[k] >= 0) xs[cur ^ 1][loff[k]] = st[k];
        }
    };

    // unroll by 2 so buffer parity is compile-time static
    for (int ii = 0; ii < FIN; ii += 2) {
        body(ii + 0, 0);
        body(ii + 1, 1);
    }

    // epilogue: guarded stores (2 px x 8 o)
    const int ho  = row0 + ty;
    const int wo0 = col0 + 2 * tx;
    if (ho < HO) {
#pragma unroll
        for (int oo = 0; oo < OCH; ++oo) {
            size_t base = ((size_t)b * FOUT + (o0 + oo)) * (size_t)(HO * WO)
                        + (size_t)ho * WO + wo0;
            if (wo0 + 0 < WO) out[base + 0] = acc[oo][0];
            if (wo0 + 1 < WO) out[base + 1] = acc[oo][1];
        }
    }
}

extern "C" void kernel_launch(void* const* d_in, const int* in_sizes, int n_in,
                              void* d_out, int out_size, void* d_ws, size_t ws_size,
                              hipStream_t stream) {
    const float* x  = (const float*)d_in[0];
    const float* Wf = (const float*)d_in[1];
    const float* bf = (const float*)d_in[2];
    const float* Wc = (const float*)d_in[3];
    const float* bc = (const float*)d_in[4];
    float* out = (float*)d_out;

    dim3 grid(32, FOUT / OCH, 4);   // 8x4 spatial tiles, 8 o-chunks, 4 batches
    hipLaunchKernelGGL(fused_dwconv_combine, grid, dim3(256), 0, stream,
                       x, Wf, bf, Wc, bc, out);
}